// Round 3
// baseline (605.622 us; speedup 1.0000x reference)
//
#include <hip/hip_runtime.h>

#define NW_   64
#define BW_   2048   // B*NW
#define L_    49
#define D_    192
#define PROJ_ 256
#define H_    8
#define HD_   32

typedef __attribute__((ext_vector_type(8))) short bf16x8;
typedef __attribute__((ext_vector_type(4))) float f32x4;

__device__ __forceinline__ short f2bf(float f) {
    union { float f; unsigned u; } v; v.f = f;
    unsigned r = v.u + 0x7FFFu + ((v.u >> 16) & 1u);   // RNE
    return (short)(r >> 16);
}

__device__ __forceinline__ bf16x8 pack8(float4 a, float4 b) {
    bf16x8 r;
    r[0] = f2bf(a.x); r[1] = f2bf(a.y); r[2] = f2bf(a.z); r[3] = f2bf(a.w);
    r[4] = f2bf(b.x); r[5] = f2bf(b.y); r[6] = f2bf(b.z); r[7] = f2bf(b.w);
    return r;
}

// ---------------------------------------------------------------------------
// Prep: weights -> bf16 transposed Wt[n][k] (k contiguous); mask -> 64-bit
// row bitmaps mbits[w][i] (bit j = mask[w][i][j]).
// grid (256, 5), block 256.
// ---------------------------------------------------------------------------
__global__ __launch_bounds__(256) void prep_kernel(
    const float* __restrict__ Wq, const float* __restrict__ Wk,
    const float* __restrict__ Wv, const float* __restrict__ Ww,
    const int* __restrict__ mask,
    short* __restrict__ Wqt, short* __restrict__ Wkt,
    short* __restrict__ Wvt, short* __restrict__ Wwt,
    unsigned long long* __restrict__ mbits)
{
    const int sel = blockIdx.y;
    const int n   = blockIdx.x;
    const int tid = threadIdx.x;
    if (sel < 3) {
        const float* src = (sel == 0) ? Wq : (sel == 1) ? Wk : Wv;
        short* dst = (sel == 0) ? Wqt : (sel == 1) ? Wkt : Wvt;
        if (tid < D_) dst[n * D_ + tid] = f2bf(src[tid * PROJ_ + n]);
    } else if (sel == 3) {
        if (n < D_) Wwt[n * PROJ_ + tid] = f2bf(Ww[tid * D_ + n]);
    } else {
        if (n < NW_ && tid < 64) {
            unsigned long long v = 0ull;
            if (tid < L_) {
                const int* mrow = mask + (n * L_ + tid) * L_;
                for (int j = 0; j < L_; ++j)
                    if (mrow[j] != 0) v |= (1ull << j);
            }
            mbits[n * 64 + tid] = v;
        }
    }
}

// ---------------------------------------------------------------------------
// Fused QKV + attention. grid 4096: block = (window, head-half); 4 waves,
// wave = one head. Per-wave LDS region (14848 B):
//   qs [64][40] @0      (q pre-scaled by 1/sqrt(32))
//   ks [64][40] @2560
//   vT [32][72] @5120
//   Pb [64][72] @0      (aliases qs+ks, after S-frags consumed)
//   Ob [64][40] @0      (aliases Pb, after P-frags consumed)
// X A-frags read direct from global with row clamped to 48 (pad rows are
// masked out of softmax; pad j cols get -inf -> P=0 so vT pad cols are inert).
// Output O: [bw*49+l][256] bf16, coalesced dwordx4 stores.
// ---------------------------------------------------------------------------
__global__ __launch_bounds__(256) void qkv_attn_kernel(
    const float* __restrict__ query, const float* __restrict__ key_,
    const float* __restrict__ value,
    const short* __restrict__ Wqt, const short* __restrict__ Wkt,
    const short* __restrict__ Wvt,
    const float* __restrict__ bq, const float* __restrict__ bk,
    const unsigned long long* __restrict__ mbits,
    short* __restrict__ O)
{
    const int bw   = blockIdx.x >> 1;
    const int hp   = blockIdx.x & 1;
    const int w    = bw & (NW_ - 1);
    const int tid  = threadIdx.x;
    const int wave = tid >> 6;
    const int lane = tid & 63;
    const int m16  = lane & 15;
    const int quad = lane >> 4;
    const int head = hp * 4 + wave;
    const int c0   = head * HD_;          // global col base of this head

    __shared__ __align__(16) short lds[4 * 7424];
    short* qs  = lds + wave * 7424;
    short* ks  = qs + 2560;
    short* vTs = qs + 5120;
    short* Pb  = qs;
    short* Ob  = qs;

    const float scale = 0.17677669529663687f;  // 1/sqrt(32)
    const size_t xrow = (size_t)bw * L_;

    // ---------------- phase 1: q, k, vT ----------------
    for (int sel = 0; sel < 3; ++sel) {
        const float* X  = (sel == 0) ? query : (sel == 1) ? key_ : value;
        const short* Wt = (sel == 0) ? Wqt : (sel == 1) ? Wkt : Wvt;

        f32x4 acc[4][2];
        #pragma unroll
        for (int mt = 0; mt < 4; ++mt)
            #pragma unroll
            for (int nt = 0; nt < 2; ++nt)
                acc[mt][nt] = (f32x4){0.f, 0.f, 0.f, 0.f};

        #pragma unroll
        for (int kc = 0; kc < 6; ++kc) {
            bf16x8 af[4], bf[2];
            #pragma unroll
            for (int mt = 0; mt < 4; ++mt) {
                int row = mt * 16 + m16; if (row > L_ - 1) row = L_ - 1;
                const float* p = &X[(xrow + row) * D_ + kc * 32 + quad * 8];
                float4 x0 = *(const float4*)p;
                float4 x1 = *(const float4*)(p + 4);
                af[mt] = pack8(x0, x1);
            }
            #pragma unroll
            for (int nt = 0; nt < 2; ++nt)
                bf[nt] = *(const bf16x8*)&Wt[(size_t)(c0 + nt * 16 + m16) * D_ + kc * 32 + quad * 8];
            #pragma unroll
            for (int mt = 0; mt < 4; ++mt)
                #pragma unroll
                for (int nt = 0; nt < 2; ++nt)
                    acc[mt][nt] = __builtin_amdgcn_mfma_f32_16x16x32_bf16(
                        af[mt], bf[nt], acc[mt][nt], 0, 0, 0);
        }

        #pragma unroll
        for (int nt = 0; nt < 2; ++nt) {
            const int col = nt * 16 + m16;
            float bias = 0.f;
            if (sel == 0) bias = bq[c0 + col];
            else if (sel == 1) bias = bk[c0 + col];
            #pragma unroll
            for (int mt = 0; mt < 4; ++mt)
                #pragma unroll
                for (int r = 0; r < 4; ++r) {
                    const int row = mt * 16 + quad * 4 + r;
                    float v = acc[mt][nt][r] + bias;
                    if (sel == 0) v *= scale;
                    if (sel == 2) vTs[col * 72 + row] = f2bf(v);
                    else if (sel == 0) qs[row * 40 + col] = f2bf(v);
                    else ks[row * 40 + col] = f2bf(v);
                }
        }
    }
    __syncthreads();   // phase-1 LDS writes complete

    // ---------------- S = q @ k^T (K=32, one chunk) ----------------
    bf16x8 saf[4], sbf[4];
    #pragma unroll
    for (int mt = 0; mt < 4; ++mt)
        saf[mt] = *(const bf16x8*)&qs[(mt * 16 + m16) * 40 + quad * 8];
    #pragma unroll
    for (int nt = 0; nt < 4; ++nt)
        sbf[nt] = *(const bf16x8*)&ks[(nt * 16 + m16) * 40 + quad * 8];
    __syncthreads();   // q/k frag reads drained before Pb (alias) writes

    f32x4 sacc[4][4];
    #pragma unroll
    for (int mt = 0; mt < 4; ++mt)
        #pragma unroll
        for (int nt = 0; nt < 4; ++nt)
            sacc[mt][nt] = (f32x4){0.f, 0.f, 0.f, 0.f};
    #pragma unroll
    for (int mt = 0; mt < 4; ++mt)
        #pragma unroll
        for (int nt = 0; nt < 4; ++nt)
            sacc[mt][nt] = __builtin_amdgcn_mfma_f32_16x16x32_bf16(
                saf[mt], sbf[nt], sacc[mt][nt], 0, 0, 0);

    // ---------------- mask + softmax (in-register) ----------------
    float inv[4][4];
    #pragma unroll
    for (int mt = 0; mt < 4; ++mt) {
        #pragma unroll
        for (int r = 0; r < 4; ++r) {
            const int i = mt * 16 + quad * 4 + r;
            const unsigned long long mb = mbits[w * 64 + i];
            float s[4];
            #pragma unroll
            for (int nt = 0; nt < 4; ++nt) {
                const int j = nt * 16 + m16;
                float v = sacc[mt][nt][r];
                if (j >= L_) v = -INFINITY;                       // pad cols: P=0
                else if (i >= L_ || ((mb >> j) & 1ull)) v = -1000.0f;
                s[nt] = v;
            }
            float mx = fmaxf(fmaxf(s[0], s[1]), fmaxf(s[2], s[3]));
            #pragma unroll
            for (int d = 1; d < 16; d <<= 1) mx = fmaxf(mx, __shfl_xor(mx, d, 64));
            float e[4], sum = 0.f;
            #pragma unroll
            for (int nt = 0; nt < 4; ++nt) { e[nt] = __expf(s[nt] - mx); sum += e[nt]; }
            #pragma unroll
            for (int d = 1; d < 16; d <<= 1) sum += __shfl_xor(sum, d, 64);
            inv[mt][r] = 1.0f / sum;
            #pragma unroll
            for (int nt = 0; nt < 4; ++nt)
                Pb[i * 72 + nt * 16 + m16] = f2bf(e[nt]);   // unnormalized
        }
    }
    __syncthreads();   // P writes complete

    // ---------------- O = P @ v (K=64) ----------------
    bf16x8 pf[2][4], vf[2][2];
    #pragma unroll
    for (int kc = 0; kc < 2; ++kc) {
        #pragma unroll
        for (int mt = 0; mt < 4; ++mt)
            pf[kc][mt] = *(const bf16x8*)&Pb[(mt * 16 + m16) * 72 + kc * 32 + quad * 8];
        #pragma unroll
        for (int nt = 0; nt < 2; ++nt)
            vf[kc][nt] = *(const bf16x8*)&vTs[(nt * 16 + m16) * 72 + kc * 32 + quad * 8];
    }
    __syncthreads();   // P frag reads drained before Ob (alias) writes

    f32x4 oacc[4][2];
    #pragma unroll
    for (int mt = 0; mt < 4; ++mt)
        #pragma unroll
        for (int nt = 0; nt < 2; ++nt)
            oacc[mt][nt] = (f32x4){0.f, 0.f, 0.f, 0.f};
    #pragma unroll
    for (int kc = 0; kc < 2; ++kc)
        #pragma unroll
        for (int mt = 0; mt < 4; ++mt)
            #pragma unroll
            for (int nt = 0; nt < 2; ++nt)
                oacc[mt][nt] = __builtin_amdgcn_mfma_f32_16x16x32_bf16(
                    pf[kc][mt], vf[kc][nt], oacc[mt][nt], 0, 0, 0);

    #pragma unroll
    for (int mt = 0; mt < 4; ++mt)
        #pragma unroll
        for (int nt = 0; nt < 2; ++nt)
            #pragma unroll
            for (int r = 0; r < 4; ++r)
                Ob[(mt * 16 + quad * 4 + r) * 40 + nt * 16 + m16] =
                    f2bf(oacc[mt][nt][r] * inv[mt][r]);
    __syncthreads();   // Ob complete

    // coalesced store: rows <49, 32 cols (64B) per row for this head
    #pragma unroll
    for (int it = 0; it < 4; ++it) {
        const int idx = it * 64 + lane;
        const int row = idx >> 2, q4 = idx & 3;
        if (row < L_) {
            bf16x8 vv = *(const bf16x8*)&Ob[row * 40 + q4 * 8];
            *(bf16x8*)&O[((xrow + row) * PROJ_ + c0 + q4 * 8)] = vv;
        }
    }
}

// ---------------------------------------------------------------------------
// Output projection: out[bw*49+l][0..191] = O[l][:] @ Wwt^T + bias.
// 2048 blocks, 4 waves; wave owns 48 cols. No LDS: A-frags direct from
// global O (rows clamped to 48), B-frags from L2-hot Wwt.
// ---------------------------------------------------------------------------
__global__ __launch_bounds__(256) void outproj_kernel(
    const short* __restrict__ O, const short* __restrict__ Wwt,
    const float* __restrict__ bwb, float* __restrict__ out)
{
    const int bw   = blockIdx.x;
    const int tid  = threadIdx.x;
    const int wave = tid >> 6;
    const int lane = tid & 63;
    const int m16  = lane & 15;
    const int quad = lane >> 4;
    const size_t xrow = (size_t)bw * L_;

    f32x4 acc[4][3];
    #pragma unroll
    for (int mt = 0; mt < 4; ++mt)
        #pragma unroll
        for (int nt = 0; nt < 3; ++nt)
            acc[mt][nt] = (f32x4){0.f, 0.f, 0.f, 0.f};

    #pragma unroll
    for (int kc = 0; kc < 8; ++kc) {
        bf16x8 af[4], bf[3];
        #pragma unroll
        for (int mt = 0; mt < 4; ++mt) {
            int row = mt * 16 + m16; if (row > L_ - 1) row = L_ - 1;
            af[mt] = *(const bf16x8*)&O[(xrow + row) * PROJ_ + kc * 32 + quad * 8];
        }
        #pragma unroll
        for (int nt = 0; nt < 3; ++nt)
            bf[nt] = *(const bf16x8*)&Wwt[(size_t)(wave * 48 + nt * 16 + m16) * PROJ_ + kc * 32 + quad * 8];
        #pragma unroll
        for (int mt = 0; mt < 4; ++mt)
            #pragma unroll
            for (int nt = 0; nt < 3; ++nt)
                acc[mt][nt] = __builtin_amdgcn_mfma_f32_16x16x32_bf16(
                    af[mt], bf[nt], acc[mt][nt], 0, 0, 0);
    }

    #pragma unroll
    for (int nt = 0; nt < 3; ++nt) {
        const int col = wave * 48 + nt * 16 + m16;
        const float bias = bwb[col];
        #pragma unroll
        for (int mt = 0; mt < 4; ++mt)
            #pragma unroll
            for (int r = 0; r < 4; ++r) {
                const int row = mt * 16 + quad * 4 + r;
                if (row < L_)
                    out[(xrow + row) * D_ + col] = acc[mt][nt][r] + bias;
            }
    }
}

extern "C" void kernel_launch(void* const* d_in, const int* in_sizes, int n_in,
                              void* d_out, int out_size, void* d_ws, size_t ws_size,
                              hipStream_t stream) {
    const float* query = (const float*)d_in[0];
    const float* key_  = (const float*)d_in[1];
    const float* value = (const float*)d_in[2];
    const int*   mask  = (const int*)d_in[3];
    const float* Wq    = (const float*)d_in[4];
    const float* bq    = (const float*)d_in[5];
    const float* Wk    = (const float*)d_in[6];
    const float* bk    = (const float*)d_in[7];
    const float* Wv    = (const float*)d_in[8];
    const float* Ww    = (const float*)d_in[9];
    const float* bw    = (const float*)d_in[10];
    float* out = (float*)d_out;

    short* O   = (short*)d_ws;                      // [2048*49][256] bf16
    short* Wqt = O + (size_t)BW_ * L_ * PROJ_;
    short* Wkt = Wqt + D_ * PROJ_;
    short* Wvt = Wkt + D_ * PROJ_;
    short* Wwt = Wvt + D_ * PROJ_;
    unsigned long long* mbits = (unsigned long long*)(Wwt + D_ * PROJ_);

    prep_kernel<<<dim3(256, 5), 256, 0, stream>>>(Wq, Wk, Wv, Ww, mask,
                                                  Wqt, Wkt, Wvt, Wwt, mbits);
    qkv_attn_kernel<<<dim3(BW_ * 2), 256, 0, stream>>>(query, key_, value,
                                                       Wqt, Wkt, Wvt, bq, bk,
                                                       mbits, O);
    outproj_kernel<<<dim3(BW_), 256, 0, stream>>>(O, Wwt, bw, out);
}